// Round 15
// baseline (218.860 us; speedup 1.0000x reference)
//
#include <hip/hip_runtime.h>
#include <hip/hip_bf16.h>

// Two-level counting-sort CSR build:
//   bucket = row >> 8  (256 rows per bucket, NBK = ceil(N/256) <= 512 for N <= 131072)
//   packed edge record = (localrow << 17) | col   (needs N <= 2^17)

#define EPB 4096   // edges per block in bucket count/scatter
#define ESCAP 5120 // LDS edge-staging cap in bucket_build (mean 4096, +16 sigma)

typedef __attribute__((ext_vector_type(8))) short bf16x8;
typedef __attribute__((ext_vector_type(4))) float f32x4;

__device__ __forceinline__ float bf2f(unsigned short u) {
    unsigned int x = ((unsigned int)u) << 16;
    return __uint_as_float(x);
}
__device__ __forceinline__ unsigned short f2bf(float f) {
    unsigned int b = __float_as_uint(f);
    unsigned int r = (b + 0x7FFF + ((b >> 16) & 1)) >> 16;  // round-nearest-even
    return (unsigned short)r;
}
__device__ __forceinline__ void acc8(float* a, bf16x8 v) {
#pragma unroll
    for (int i = 0; i < 8; ++i) a[i] += bf2f((unsigned short)(short)v[i]);
}
// masked accumulate: adds exact 0.0f for masked-off lanes (identity)
__device__ __forceinline__ void acc8m(float* a, bf16x8 v, bool m) {
#pragma unroll
    for (int i = 0; i < 8; ++i) a[i] += m ? bf2f((unsigned short)(short)v[i]) : 0.0f;
}

// ---- one-shot weight convert+pack to MFMA fragment order (+ bcnt zeroing) ----
// packed idx = ((kt*NT + nt)*4 + g)*128 + m*8 + i
//   <-> source  k = (kt&1)*32 + g*8 + i (from W0 if kt<2 else W1), col = nt*16 + m
template <int NC>
__device__ __forceinline__ void pack_pair(const float* __restrict__ W0,
                                          const float* __restrict__ W1,
                                          unsigned short* __restrict__ out, int idx) {
    constexpr int NT = NC / 16;
    int i = idx & 7;
    int m = (idx >> 3) & 15;
    int g = (idx >> 7) & 3;
    int f = idx >> 9;  // kt*NT + nt
    int nt = f % NT;
    int kt = f / NT;
    const float* W = (kt < 2) ? W0 : W1;
    int k = (kt & 1) * 32 + g * 8 + i;
    out[idx] = f2bf(W[k * NC + nt * 16 + m]);
}

__global__ __launch_bounds__(256) void wconv_all(const float* __restrict__ W1_0,
                                                 const float* __restrict__ W1_1,
                                                 const float* __restrict__ Wx_0,
                                                 const float* __restrict__ Wx_1,
                                                 const float* __restrict__ W2_0,
                                                 const float* __restrict__ W2_1,
                                                 unsigned short* __restrict__ wp1,
                                                 unsigned short* __restrict__ wpx,
                                                 unsigned short* __restrict__ wp2,
                                                 int* __restrict__ bcnt, int nbk) {
    int idx = blockIdx.x * 256 + threadIdx.x;
    if (idx < nbk) bcnt[idx] = 0;
    if (idx < 8192) pack_pair<64>(W1_0, W1_1, wp1, idx);
    else if (idx < 16384) pack_pair<64>(Wx_0, Wx_1, wpx, idx - 8192);
    else if (idx < 18432) pack_pair<16>(W2_0, W2_1, wp2, idx - 16384);
}

// ---- Pass A1: per-bucket edge counts ----
__global__ __launch_bounds__(256) void bucket_count(const int* __restrict__ row,
                                                    int* __restrict__ bcnt,
                                                    int e, int nbk) {
    __shared__ int bh[512];
    int tid = threadIdx.x;
    for (int j = tid; j < nbk; j += 256) bh[j] = 0;
    __syncthreads();
    int base = blockIdx.x * EPB;
#pragma unroll
    for (int k = 0; k < EPB / 256; ++k) {
        int i = base + k * 256 + tid;
        if (i < e) atomicAdd(&bh[row[i] >> 8], 1);
    }
    __syncthreads();
    for (int j = tid; j < nbk; j += 256) {
        int c = bh[j];
        if (c) atomicAdd(&bcnt[j], c);
    }
}

// ---- Pass A2: scan bucket counts (single block) ----
__global__ __launch_bounds__(256) void bucket_scan(const int* __restrict__ bcnt,
                                                   int* __restrict__ bbase,
                                                   int* __restrict__ bcursor,
                                                   int* __restrict__ off,
                                                   int nbk, int n, int e) {
    __shared__ int sa[512], sb[512];
    int tid = threadIdx.x;
    for (int j = tid; j < 512; j += 256) sa[j] = (j < nbk) ? bcnt[j] : 0;
    __syncthreads();
    int* in = sa;
    int* out = sb;
    for (int d = 1; d < 512; d <<= 1) {
        for (int j = tid; j < 512; j += 256)
            out[j] = in[j] + ((j >= d) ? in[j - d] : 0);
        __syncthreads();
        int* t = in; in = out; out = t;
    }
    for (int j = tid; j < nbk; j += 256) {
        int incl = in[j];
        int excl = incl - bcnt[j];
        bbase[j] = excl;
        bcursor[j] = excl;
        if (j == nbk - 1) bbase[nbk] = incl;
    }
    if (tid == 0) off[n] = e;
}

// ---- Pass A3: scatter packed edges into bucket regions ----
__global__ __launch_bounds__(256) void bucket_scatter(const int* __restrict__ row,
                                                      const int* __restrict__ col,
                                                      int* __restrict__ bcursor,
                                                      int* __restrict__ packed,
                                                      int e, int nbk) {
    __shared__ int bh[512];
    __shared__ int bbase[512];
    __shared__ int bcur[512];
    int tid = threadIdx.x;
    for (int j = tid; j < nbk; j += 256) { bh[j] = 0; bcur[j] = 0; }
    __syncthreads();
    int base = blockIdx.x * EPB;
#pragma unroll
    for (int k = 0; k < EPB / 256; ++k) {
        int i = base + k * 256 + tid;
        if (i < e) atomicAdd(&bh[row[i] >> 8], 1);
    }
    __syncthreads();
    for (int j = tid; j < nbk; j += 256) {
        int c = bh[j];
        bbase[j] = c ? atomicAdd(&bcursor[j], c) : 0;
    }
    __syncthreads();
#pragma unroll
    for (int k = 0; k < EPB / 256; ++k) {
        int i = base + k * 256 + tid;
        if (i < e) {
            int r = row[i];
            int b = r >> 8;
            int slot = bbase[b] + atomicAdd(&bcur[b], 1);
            packed[slot] = ((r & 255) << 17) | col[i];
        }
    }
}

// ---- Pass B: per-bucket row histogram + scan -> off/dis/csr; per-row column
//      sort (gather-locality opt, round 15); fused y/xb scale ----
__global__ __launch_bounds__(256) void bucket_build(const int* __restrict__ packed,
                                                    const int* __restrict__ bbase,
                                                    const float* __restrict__ x,
                                                    int* __restrict__ off,
                                                    float* __restrict__ dis,
                                                    int* __restrict__ csr,
                                                    unsigned short* __restrict__ y,
                                                    unsigned short* __restrict__ xb,
                                                    int n) {
    __shared__ int rcnt[256];
    __shared__ int sa[256], sb[256];
    __shared__ float disv[256];
    __shared__ int es[ESCAP];  // edge staging for sort (20 KB)
    int tid = threadIdx.x;
    int b = blockIdx.x;
    int ebase = bbase[b], eend = bbase[b + 1];
    int ecnt = eend - ebase;
    bool fit = (ecnt <= ESCAP);
    rcnt[tid] = 0;
    __syncthreads();
    for (int e = ebase + tid; e < eend; e += 256)
        atomicAdd(&rcnt[packed[e] >> 17], 1);
    __syncthreads();
    sa[tid] = rcnt[tid];
    __syncthreads();
    int* in = sa;
    int* out = sb;
    for (int d = 1; d < 256; d <<= 1) {
        out[tid] = in[tid] + ((tid >= d) ? in[tid - d] : 0);
        __syncthreads();
        int* t = in; in = out; out = t;
    }
    // in[tid] = inclusive scan; out is free for reuse as cursor
    int grow = b * 256 + tid;
    int c = rcnt[tid];
    int excl = in[tid] - c;
    float dv = (c > 0) ? rsqrtf((float)c) : 0.0f;
    disv[tid] = dv;
    if (grow < n) {
        off[grow] = ebase + excl;
        dis[grow] = dv;
    }
    out[tid] = excl;
    __syncthreads();
    if (fit) {
        // fill into LDS, sort each row's segment by column, write back coalesced.
        // Sorting is a pure locality optimization: co-resident blocks then walk
        // ascending columns together -> gather working set becomes a narrow
        // column band (L2-resident) instead of all of y. Only perturbs the
        // fp32 accumulation order (~1e-7 relative).
        for (int e = ebase + tid; e < eend; e += 256) {
            int p = packed[e];
            int lr = p >> 17;
            int pos = atomicAdd(&out[lr], 1);
            es[pos] = p & 0x1FFFF;
        }
        __syncthreads();
        if (grow < n && c > 1) {
            int s = excl;
            for (int i = s + 1; i < s + c; ++i) {
                int v = es[i];
                int j = i - 1;
                while (j >= s && es[j] > v) { es[j + 1] = es[j]; --j; }
                es[j + 1] = v;
            }
        }
        __syncthreads();
        for (int i = tid; i < ecnt; i += 256) csr[ebase + i] = es[i];
    } else {
        for (int e = ebase + tid; e < eend; e += 256) {
            int p = packed[e];
            int lr = p >> 17;
            int pos = atomicAdd(&out[lr], 1);
            csr[ebase + pos] = p & 0x1FFFF;
        }
    }
    // fused scale pass: y = bf16(dis*x), xb = bf16(x) for this bucket's 256 rows
    for (int idx = tid; idx < 4096; idx += 256) {
        int rr = idx >> 4, q = idx & 15;
        int R = b * 256 + rr;
        if (R < n) {
            float d = disv[rr];
            float4 v = ((const float4*)x)[(size_t)R * 16 + q];
            ushort4 o = {f2bf(v.x * d), f2bf(v.y * d), f2bf(v.z * d), f2bf(v.w * d)};
            ((ushort4*)y)[(size_t)R * 16 + q] = o;
            ushort4 xo = {f2bf(v.x), f2bf(v.y), f2bf(v.z), f2bf(v.w)};
            ((ushort4*)xb)[(size_t)R * 16 + q] = xo;
        }
    }
}

// ---------------- fused aggregate + dense (round-13 geometry, best measured) ----------------
// Phase 1: 64 rows/block, 4 threads/row gather 16 feats each from y[col] (bf16),
//          masked 4-edge quads (clamped csr index, exact +0.0f for OOB lanes).
// Phase 2: 4 waves x 16-row MFMA tiles (verified mapping):
//          A halves from global A0 (k 0..63) and LDS tx (k 64..127, XOR-swizzled
//          16B units: byte ^= (row&7)<<4), B frags pre-packed by wconv_all,
//          D: col=lane&15, row=4*(lane>>4)+reg.

template <int NC, bool RELU, bool WRITE_HY>
__global__ __launch_bounds__(256) void agg_dense(const unsigned short* __restrict__ y,
                                                 const unsigned short* __restrict__ A0,
                                                 const int* __restrict__ csr,
                                                 const int* __restrict__ off,
                                                 const float* __restrict__ dis,
                                                 const unsigned short* __restrict__ Wp,
                                                 const float* __restrict__ bias,
                                                 unsigned short* __restrict__ hout,
                                                 unsigned short* __restrict__ yout,
                                                 float* __restrict__ fout,
                                                 int n) {
    constexpr int NT = NC / 16;
    __shared__ unsigned short txl[64 * 64];  // 8 KB, [row][col] bf16, swizzled
    int tid = threadIdx.x;

    // ---- phase 1: gather ----
    int row_l = tid >> 2;  // 0..63
    int fq = tid & 3;      // 16-feature quarter
    int r = blockIdx.x * 64 + row_l;
    float acc16[16];
#pragma unroll
    for (int i = 0; i < 16; ++i) acc16[i] = 0.f;
    float d = 0.f;
    if (r < n) {
        int s0 = off[r], e1 = off[r + 1];
        const unsigned short* Yb = y + fq * 16;
        int e1m = e1 - 1;
        for (int t = s0; t < e1; t += 4) {
            int t1 = (t + 1 < e1) ? t + 1 : e1m;
            int t2 = (t + 2 < e1) ? t + 2 : e1m;
            int t3 = (t + 3 < e1) ? t + 3 : e1m;
            int c0 = csr[t], c1 = csr[t1], c2 = csr[t2], c3 = csr[t3];
            const bf16x8* p0 = (const bf16x8*)(Yb + (size_t)c0 * 64);
            const bf16x8* p1 = (const bf16x8*)(Yb + (size_t)c1 * 64);
            const bf16x8* p2 = (const bf16x8*)(Yb + (size_t)c2 * 64);
            const bf16x8* p3 = (const bf16x8*)(Yb + (size_t)c3 * 64);
            bf16x8 v00 = p0[0], v01 = p0[1];
            bf16x8 v10 = p1[0], v11 = p1[1];
            bf16x8 v20 = p2[0], v21 = p2[1];
            bf16x8 v30 = p3[0], v31 = p3[1];
            bool m1 = t + 1 < e1, m2 = t + 2 < e1, m3 = t + 3 < e1;
            acc8(acc16, v00); acc8(acc16 + 8, v01);
            acc8m(acc16, v10, m1); acc8m(acc16 + 8, v11, m1);
            acc8m(acc16, v20, m2); acc8m(acc16 + 8, v21, m2);
            acc8m(acc16, v30, m3); acc8m(acc16 + 8, v31, m3);
        }
        d = -dis[r];
    }
    bf16x8 ov0, ov1;
#pragma unroll
    for (int i = 0; i < 8; ++i) {
        ov0[i] = (short)f2bf(acc16[i] * d);
        ov1[i] = (short)f2bf(acc16[8 + i] * d);
    }
    int swz = (row_l & 7) << 4;
    int cb = fq * 32;
    *(bf16x8*)((char*)txl + row_l * 128 + (cb ^ swz)) = ov0;
    *(bf16x8*)((char*)txl + row_l * 128 + ((cb + 16) ^ swz)) = ov1;
    __syncthreads();

    // ---- phase 2: MFMA ----
    int lane = tid & 63;
    int m = lane & 15;
    int g = lane >> 4;
    int w = tid >> 6;
    const bf16x8* WP = (const bf16x8*)Wp;
    bf16x8 bf[NT][4];
#pragma unroll
    for (int kt = 0; kt < 4; ++kt)
#pragma unroll
        for (int nt = 0; nt < NT; ++nt)
            bf[nt][kt] = WP[((kt * NT + nt) * 4 + g) * 16 + m];
    int r0 = blockIdx.x * 64 + w * 16;
    int ra = r0 + m;
    if (ra > n - 1) ra = n - 1;  // clamped read; write masked below
    const unsigned short* q0 = A0 + (size_t)ra * 64 + g * 8;
    bf16x8 a0 = *(const bf16x8*)q0;
    bf16x8 a1 = *(const bf16x8*)(q0 + 32);
    int rl2 = w * 16 + m;  // rl2 & 7 == m & 7 (w*16 is a multiple of 16)
    int sw2 = (m & 7) << 4;
    bf16x8 a2 = *(bf16x8*)((char*)txl + rl2 * 128 + ((g * 16) ^ sw2));
    bf16x8 a3 = *(bf16x8*)((char*)txl + rl2 * 128 + ((64 + g * 16) ^ sw2));
    f32x4 acc[NT];
#pragma unroll
    for (int nt = 0; nt < NT; ++nt) {
        float b = bias[nt * 16 + m];
        acc[nt][0] = b; acc[nt][1] = b; acc[nt][2] = b; acc[nt][3] = b;
    }
#pragma unroll
    for (int nt = 0; nt < NT; ++nt) {
        acc[nt] = __builtin_amdgcn_mfma_f32_16x16x32_bf16(a0, bf[nt][0], acc[nt], 0, 0, 0);
        acc[nt] = __builtin_amdgcn_mfma_f32_16x16x32_bf16(a1, bf[nt][1], acc[nt], 0, 0, 0);
        acc[nt] = __builtin_amdgcn_mfma_f32_16x16x32_bf16(a2, bf[nt][2], acc[nt], 0, 0, 0);
        acc[nt] = __builtin_amdgcn_mfma_f32_16x16x32_bf16(a3, bf[nt][3], acc[nt], 0, 0, 0);
    }
#pragma unroll
    for (int reg = 0; reg < 4; ++reg) {
        int rr = r0 + 4 * g + reg;
        if (rr >= n) continue;
        if (WRITE_HY) {
            float dv = dis[rr];
#pragma unroll
            for (int nt = 0; nt < NT; ++nt) {
                float v = acc[nt][reg];
                if (RELU) v = fmaxf(v, 0.f);
                hout[(size_t)rr * NC + nt * 16 + m] = f2bf(v);
                yout[(size_t)rr * NC + nt * 16 + m] = f2bf(v * dv);
            }
        } else {
#pragma unroll
            for (int nt = 0; nt < NT; ++nt)
                fout[(size_t)rr * NC + nt * 16 + m] = acc[nt][reg];
        }
    }
}

// ---------------- launch ----------------

extern "C" void kernel_launch(void* const* d_in, const int* in_sizes, int n_in,
                              void* d_out, int out_size, void* d_ws, size_t ws_size,
                              hipStream_t stream) {
    const float* x    = (const float*)d_in[0];
    const int*   adj  = (const int*)d_in[1];
    const float* W1_0 = (const float*)d_in[2];
    const float* W1_1 = (const float*)d_in[3];
    const float* b1   = (const float*)d_in[4];
    const float* Wx_0 = (const float*)d_in[5];
    const float* Wx_1 = (const float*)d_in[6];
    const float* bx   = (const float*)d_in[7];
    const float* W2_0 = (const float*)d_in[8];
    const float* W2_1 = (const float*)d_in[9];
    const float* b2   = (const float*)d_in[10];
    float* out = (float*)d_out;

    int N = in_sizes[0] / 64;
    int E = in_sizes[1] / 2;
    const int* row = adj;
    const int* col = adj + E;
    int NBK = (N + 255) / 256;  // rows bucketed by row>>8; requires N <= 131072

    char* p = (char*)d_ws;
    auto alloc = [&](size_t bytes) {
        char* q = p;
        p += (bytes + 255) & ~(size_t)255;
        return q;
    };
    int*   bcnt  = (int*)alloc((size_t)(NBK) * 4);
    int*   bbase = (int*)alloc((size_t)(NBK + 1) * 4);
    int*   bcur  = (int*)alloc((size_t)(NBK) * 4);
    int*   off   = (int*)alloc((size_t)(N + 1) * 4);
    float* dis   = (float*)alloc((size_t)N * 4);
    int*   csr   = (int*)alloc((size_t)E * 4);
    int*   packed = (int*)alloc((size_t)E * 4);
    unsigned short* wp1 = (unsigned short*)alloc(8192 * 2);
    unsigned short* wpx = (unsigned short*)alloc(8192 * 2);
    unsigned short* wp2 = (unsigned short*)alloc(2048 * 2);
    unsigned short* y  = (unsigned short*)alloc((size_t)N * 64 * 2);
    unsigned short* y2 = (unsigned short*)alloc((size_t)N * 64 * 2);
    unsigned short* xb = (unsigned short*)alloc((size_t)N * 64 * 2);
    unsigned short* h  = (unsigned short*)alloc((size_t)N * 64 * 2);
    unsigned short* h2 = (unsigned short*)alloc((size_t)N * 64 * 2);
    (void)ws_size;

    int EB = (E + EPB - 1) / EPB;
    wconv_all<<<72, 256, 0, stream>>>(W1_0, W1_1, Wx_0, Wx_1, W2_0, W2_1,
                                      wp1, wpx, wp2, bcnt, NBK);
    bucket_count<<<EB, 256, 0, stream>>>(row, bcnt, E, NBK);
    bucket_scan<<<1, 256, 0, stream>>>(bcnt, bbase, bcur, off, NBK, N, E);
    bucket_scatter<<<EB, 256, 0, stream>>>(row, col, bcur, packed, E, NBK);
    bucket_build<<<NBK, 256, 0, stream>>>(packed, bbase, x, off, dis, csr, y, xb, N);

    int nb64 = (N + 63) / 64;
    // layer 1: gather from y, dense on [xb | tx] -> h, next-layer y2
    agg_dense<64, true, true><<<nb64, 256, 0, stream>>>(y, xb, csr, off, dis, wp1, b1, h, y2, nullptr, N);
    // layer x: gather from y2, dense on [h | tx] -> h2, next-layer y
    agg_dense<64, true, true><<<nb64, 256, 0, stream>>>(y2, h, csr, off, dis, wpx, bx, h2, y, nullptr, N);
    // layer 2: gather from y, dense on [h2 | tx] -> out (fp32)
    agg_dense<16, false, false><<<nb64, 256, 0, stream>>>(y, h2, csr, off, dis, wp2, b2, nullptr, nullptr, out, N);
}

// Round 16
// 186.164 us; speedup vs baseline: 1.1756x; 1.1756x over previous
//
#include <hip/hip_runtime.h>
#include <hip/hip_bf16.h>

// Two-level counting-sort CSR build:
//   bucket = row >> 8  (256 rows per bucket, NBK = ceil(N/256) <= 512 for N <= 131072)
//   packed edge record = (localrow << 17) | col   (needs N <= 2^17)

#define EPB 4096  // edges per block in bucket count/scatter

typedef __attribute__((ext_vector_type(8))) short bf16x8;
typedef __attribute__((ext_vector_type(4))) float f32x4;

__device__ __forceinline__ float bf2f(unsigned short u) {
    unsigned int x = ((unsigned int)u) << 16;
    return __uint_as_float(x);
}
__device__ __forceinline__ unsigned short f2bf(float f) {
    unsigned int b = __float_as_uint(f);
    unsigned int r = (b + 0x7FFF + ((b >> 16) & 1)) >> 16;  // round-nearest-even
    return (unsigned short)r;
}
__device__ __forceinline__ void acc8(float* a, bf16x8 v) {
#pragma unroll
    for (int i = 0; i < 8; ++i) a[i] += bf2f((unsigned short)(short)v[i]);
}
// masked accumulate: adds exact 0.0f for masked-off lanes (identity)
__device__ __forceinline__ void acc8m(float* a, bf16x8 v, bool m) {
#pragma unroll
    for (int i = 0; i < 8; ++i) a[i] += m ? bf2f((unsigned short)(short)v[i]) : 0.0f;
}

// ---- one-shot weight convert+pack to MFMA fragment order (+ bcnt zeroing) ----
// packed idx = ((kt*NT + nt)*4 + g)*128 + m*8 + i
//   <-> source  k = (kt&1)*32 + g*8 + i (from W0 if kt<2 else W1), col = nt*16 + m
template <int NC>
__device__ __forceinline__ void pack_pair(const float* __restrict__ W0,
                                          const float* __restrict__ W1,
                                          unsigned short* __restrict__ out, int idx) {
    constexpr int NT = NC / 16;
    int i = idx & 7;
    int m = (idx >> 3) & 15;
    int g = (idx >> 7) & 3;
    int f = idx >> 9;  // kt*NT + nt
    int nt = f % NT;
    int kt = f / NT;
    const float* W = (kt < 2) ? W0 : W1;
    int k = (kt & 1) * 32 + g * 8 + i;
    out[idx] = f2bf(W[k * NC + nt * 16 + m]);
}

__global__ __launch_bounds__(256) void wconv_all(const float* __restrict__ W1_0,
                                                 const float* __restrict__ W1_1,
                                                 const float* __restrict__ Wx_0,
                                                 const float* __restrict__ Wx_1,
                                                 const float* __restrict__ W2_0,
                                                 const float* __restrict__ W2_1,
                                                 unsigned short* __restrict__ wp1,
                                                 unsigned short* __restrict__ wpx,
                                                 unsigned short* __restrict__ wp2,
                                                 int* __restrict__ bcnt, int nbk) {
    int idx = blockIdx.x * 256 + threadIdx.x;
    if (idx < nbk) bcnt[idx] = 0;
    if (idx < 8192) pack_pair<64>(W1_0, W1_1, wp1, idx);
    else if (idx < 16384) pack_pair<64>(Wx_0, Wx_1, wpx, idx - 8192);
    else if (idx < 18432) pack_pair<16>(W2_0, W2_1, wp2, idx - 16384);
}

// ---- Pass A1: per-bucket edge counts ----
__global__ __launch_bounds__(256) void bucket_count(const int* __restrict__ row,
                                                    int* __restrict__ bcnt,
                                                    int e, int nbk) {
    __shared__ int bh[512];
    int tid = threadIdx.x;
    for (int j = tid; j < nbk; j += 256) bh[j] = 0;
    __syncthreads();
    int base = blockIdx.x * EPB;
#pragma unroll
    for (int k = 0; k < EPB / 256; ++k) {
        int i = base + k * 256 + tid;
        if (i < e) atomicAdd(&bh[row[i] >> 8], 1);
    }
    __syncthreads();
    for (int j = tid; j < nbk; j += 256) {
        int c = bh[j];
        if (c) atomicAdd(&bcnt[j], c);
    }
}

// ---- Pass A2: scan bucket counts (single block) ----
__global__ __launch_bounds__(256) void bucket_scan(const int* __restrict__ bcnt,
                                                   int* __restrict__ bbase,
                                                   int* __restrict__ bcursor,
                                                   int* __restrict__ off,
                                                   int nbk, int n, int e) {
    __shared__ int sa[512], sb[512];
    int tid = threadIdx.x;
    for (int j = tid; j < 512; j += 256) sa[j] = (j < nbk) ? bcnt[j] : 0;
    __syncthreads();
    int* in = sa;
    int* out = sb;
    for (int d = 1; d < 512; d <<= 1) {
        for (int j = tid; j < 512; j += 256)
            out[j] = in[j] + ((j >= d) ? in[j - d] : 0);
        __syncthreads();
        int* t = in; in = out; out = t;
    }
    for (int j = tid; j < nbk; j += 256) {
        int incl = in[j];
        int excl = incl - bcnt[j];
        bbase[j] = excl;
        bcursor[j] = excl;
        if (j == nbk - 1) bbase[nbk] = incl;
    }
    if (tid == 0) off[n] = e;
}

// ---- Pass A3: scatter packed edges into bucket regions ----
__global__ __launch_bounds__(256) void bucket_scatter(const int* __restrict__ row,
                                                      const int* __restrict__ col,
                                                      int* __restrict__ bcursor,
                                                      int* __restrict__ packed,
                                                      int e, int nbk) {
    __shared__ int bh[512];
    __shared__ int bbase[512];
    __shared__ int bcur[512];
    int tid = threadIdx.x;
    for (int j = tid; j < nbk; j += 256) { bh[j] = 0; bcur[j] = 0; }
    __syncthreads();
    int base = blockIdx.x * EPB;
#pragma unroll
    for (int k = 0; k < EPB / 256; ++k) {
        int i = base + k * 256 + tid;
        if (i < e) atomicAdd(&bh[row[i] >> 8], 1);
    }
    __syncthreads();
    for (int j = tid; j < nbk; j += 256) {
        int c = bh[j];
        bbase[j] = c ? atomicAdd(&bcursor[j], c) : 0;
    }
    __syncthreads();
#pragma unroll
    for (int k = 0; k < EPB / 256; ++k) {
        int i = base + k * 256 + tid;
        if (i < e) {
            int r = row[i];
            int b = r >> 8;
            int slot = bbase[b] + atomicAdd(&bcur[b], 1);
            packed[slot] = ((r & 255) << 17) | col[i];
        }
    }
}

// ---- Pass B: per-bucket row histogram + scan -> off/dis/csr; fused y/xb scale ----
__global__ __launch_bounds__(256) void bucket_build(const int* __restrict__ packed,
                                                    const int* __restrict__ bbase,
                                                    const float* __restrict__ x,
                                                    int* __restrict__ off,
                                                    float* __restrict__ dis,
                                                    int* __restrict__ csr,
                                                    unsigned short* __restrict__ y,
                                                    unsigned short* __restrict__ xb,
                                                    int n) {
    __shared__ int rcnt[256];
    __shared__ int sa[256], sb[256];
    __shared__ float disv[256];
    int tid = threadIdx.x;
    int b = blockIdx.x;
    int ebase = bbase[b], eend = bbase[b + 1];
    rcnt[tid] = 0;
    __syncthreads();
    for (int e = ebase + tid; e < eend; e += 256)
        atomicAdd(&rcnt[packed[e] >> 17], 1);
    __syncthreads();
    sa[tid] = rcnt[tid];
    __syncthreads();
    int* in = sa;
    int* out = sb;
    for (int d = 1; d < 256; d <<= 1) {
        out[tid] = in[tid] + ((tid >= d) ? in[tid - d] : 0);
        __syncthreads();
        int* t = in; in = out; out = t;
    }
    // in[tid] = inclusive scan; out is free for reuse as cursor
    int grow = b * 256 + tid;
    int c = rcnt[tid];
    int excl = in[tid] - c;
    float dv = (c > 0) ? rsqrtf((float)c) : 0.0f;
    disv[tid] = dv;
    if (grow < n) {
        off[grow] = ebase + excl;
        dis[grow] = dv;
    }
    out[tid] = excl;
    __syncthreads();
    for (int e = ebase + tid; e < eend; e += 256) {
        int p = packed[e];
        int lr = p >> 17;
        int pos = atomicAdd(&out[lr], 1);
        csr[ebase + pos] = p & 0x1FFFF;
    }
    // fused scale pass: y = bf16(dis*x), xb = bf16(x) for this bucket's 256 rows
    for (int idx = tid; idx < 4096; idx += 256) {
        int rr = idx >> 4, q = idx & 15;
        int R = b * 256 + rr;
        if (R < n) {
            float d = disv[rr];
            float4 v = ((const float4*)x)[(size_t)R * 16 + q];
            ushort4 o = {f2bf(v.x * d), f2bf(v.y * d), f2bf(v.z * d), f2bf(v.w * d)};
            ((ushort4*)y)[(size_t)R * 16 + q] = o;
            ushort4 xo = {f2bf(v.x), f2bf(v.y), f2bf(v.z), f2bf(v.w)};
            ((ushort4*)xb)[(size_t)R * 16 + q] = xo;
        }
    }
}

// ---------------- fused aggregate + dense (round-13 geometry + masked tail) ----------------
// Phase 1: 64 rows/block, 4 threads/row gather 16 feats each from y[col] (bf16),
//          masked 4-edge quads (clamped csr index, exact +0.0f for OOB lanes):
//          every row runs pure 8-loads-in-flight rounds, no serial remainder.
// Phase 2: 4 waves x 16-row MFMA tiles (verified mapping):
//          A halves from global A0 (k 0..63) and LDS tx (k 64..127, XOR-swizzled
//          16B units: byte ^= (row&7)<<4), B frags pre-packed by wconv_all,
//          D: col=lane&15, row=4*(lane>>4)+reg.

template <int NC, bool RELU, bool WRITE_HY>
__global__ __launch_bounds__(256) void agg_dense(const unsigned short* __restrict__ y,
                                                 const unsigned short* __restrict__ A0,
                                                 const int* __restrict__ csr,
                                                 const int* __restrict__ off,
                                                 const float* __restrict__ dis,
                                                 const unsigned short* __restrict__ Wp,
                                                 const float* __restrict__ bias,
                                                 unsigned short* __restrict__ hout,
                                                 unsigned short* __restrict__ yout,
                                                 float* __restrict__ fout,
                                                 int n) {
    constexpr int NT = NC / 16;
    __shared__ unsigned short txl[64 * 64];  // 8 KB, [row][col] bf16, swizzled
    int tid = threadIdx.x;

    // ---- phase 1: gather ----
    int row_l = tid >> 2;  // 0..63
    int fq = tid & 3;      // 16-feature quarter
    int r = blockIdx.x * 64 + row_l;
    float acc16[16];
#pragma unroll
    for (int i = 0; i < 16; ++i) acc16[i] = 0.f;
    float d = 0.f;
    if (r < n) {
        int s0 = off[r], e1 = off[r + 1];
        const unsigned short* Yb = y + fq * 16;
        int e1m = e1 - 1;
        for (int t = s0; t < e1; t += 4) {
            int t1 = (t + 1 < e1) ? t + 1 : e1m;
            int t2 = (t + 2 < e1) ? t + 2 : e1m;
            int t3 = (t + 3 < e1) ? t + 3 : e1m;
            int c0 = csr[t], c1 = csr[t1], c2 = csr[t2], c3 = csr[t3];
            const bf16x8* p0 = (const bf16x8*)(Yb + (size_t)c0 * 64);
            const bf16x8* p1 = (const bf16x8*)(Yb + (size_t)c1 * 64);
            const bf16x8* p2 = (const bf16x8*)(Yb + (size_t)c2 * 64);
            const bf16x8* p3 = (const bf16x8*)(Yb + (size_t)c3 * 64);
            bf16x8 v00 = p0[0], v01 = p0[1];
            bf16x8 v10 = p1[0], v11 = p1[1];
            bf16x8 v20 = p2[0], v21 = p2[1];
            bf16x8 v30 = p3[0], v31 = p3[1];
            bool m1 = t + 1 < e1, m2 = t + 2 < e1, m3 = t + 3 < e1;
            acc8(acc16, v00); acc8(acc16 + 8, v01);
            acc8m(acc16, v10, m1); acc8m(acc16 + 8, v11, m1);
            acc8m(acc16, v20, m2); acc8m(acc16 + 8, v21, m2);
            acc8m(acc16, v30, m3); acc8m(acc16 + 8, v31, m3);
        }
        d = -dis[r];
    }
    bf16x8 ov0, ov1;
#pragma unroll
    for (int i = 0; i < 8; ++i) {
        ov0[i] = (short)f2bf(acc16[i] * d);
        ov1[i] = (short)f2bf(acc16[8 + i] * d);
    }
    int swz = (row_l & 7) << 4;
    int cb = fq * 32;
    *(bf16x8*)((char*)txl + row_l * 128 + (cb ^ swz)) = ov0;
    *(bf16x8*)((char*)txl + row_l * 128 + ((cb + 16) ^ swz)) = ov1;
    __syncthreads();

    // ---- phase 2: MFMA ----
    int lane = tid & 63;
    int m = lane & 15;
    int g = lane >> 4;
    int w = tid >> 6;
    const bf16x8* WP = (const bf16x8*)Wp;
    bf16x8 bf[NT][4];
#pragma unroll
    for (int kt = 0; kt < 4; ++kt)
#pragma unroll
        for (int nt = 0; nt < NT; ++nt)
            bf[nt][kt] = WP[((kt * NT + nt) * 4 + g) * 16 + m];
    int r0 = blockIdx.x * 64 + w * 16;
    int ra = r0 + m;
    if (ra > n - 1) ra = n - 1;  // clamped read; write masked below
    const unsigned short* q0 = A0 + (size_t)ra * 64 + g * 8;
    bf16x8 a0 = *(const bf16x8*)q0;
    bf16x8 a1 = *(const bf16x8*)(q0 + 32);
    int rl2 = w * 16 + m;  // rl2 & 7 == m & 7 (w*16 is a multiple of 16)
    int sw2 = (m & 7) << 4;
    bf16x8 a2 = *(bf16x8*)((char*)txl + rl2 * 128 + ((g * 16) ^ sw2));
    bf16x8 a3 = *(bf16x8*)((char*)txl + rl2 * 128 + ((64 + g * 16) ^ sw2));
    f32x4 acc[NT];
#pragma unroll
    for (int nt = 0; nt < NT; ++nt) {
        float b = bias[nt * 16 + m];
        acc[nt][0] = b; acc[nt][1] = b; acc[nt][2] = b; acc[nt][3] = b;
    }
#pragma unroll
    for (int nt = 0; nt < NT; ++nt) {
        acc[nt] = __builtin_amdgcn_mfma_f32_16x16x32_bf16(a0, bf[nt][0], acc[nt], 0, 0, 0);
        acc[nt] = __builtin_amdgcn_mfma_f32_16x16x32_bf16(a1, bf[nt][1], acc[nt], 0, 0, 0);
        acc[nt] = __builtin_amdgcn_mfma_f32_16x16x32_bf16(a2, bf[nt][2], acc[nt], 0, 0, 0);
        acc[nt] = __builtin_amdgcn_mfma_f32_16x16x32_bf16(a3, bf[nt][3], acc[nt], 0, 0, 0);
    }
#pragma unroll
    for (int reg = 0; reg < 4; ++reg) {
        int rr = r0 + 4 * g + reg;
        if (rr >= n) continue;
        if (WRITE_HY) {
            float dv = dis[rr];
#pragma unroll
            for (int nt = 0; nt < NT; ++nt) {
                float v = acc[nt][reg];
                if (RELU) v = fmaxf(v, 0.f);
                hout[(size_t)rr * NC + nt * 16 + m] = f2bf(v);
                yout[(size_t)rr * NC + nt * 16 + m] = f2bf(v * dv);
            }
        } else {
#pragma unroll
            for (int nt = 0; nt < NT; ++nt)
                fout[(size_t)rr * NC + nt * 16 + m] = acc[nt][reg];
        }
    }
}

// ---------------- launch ----------------

extern "C" void kernel_launch(void* const* d_in, const int* in_sizes, int n_in,
                              void* d_out, int out_size, void* d_ws, size_t ws_size,
                              hipStream_t stream) {
    const float* x    = (const float*)d_in[0];
    const int*   adj  = (const int*)d_in[1];
    const float* W1_0 = (const float*)d_in[2];
    const float* W1_1 = (const float*)d_in[3];
    const float* b1   = (const float*)d_in[4];
    const float* Wx_0 = (const float*)d_in[5];
    const float* Wx_1 = (const float*)d_in[6];
    const float* bx   = (const float*)d_in[7];
    const float* W2_0 = (const float*)d_in[8];
    const float* W2_1 = (const float*)d_in[9];
    const float* b2   = (const float*)d_in[10];
    float* out = (float*)d_out;

    int N = in_sizes[0] / 64;
    int E = in_sizes[1] / 2;
    const int* row = adj;
    const int* col = adj + E;
    int NBK = (N + 255) / 256;  // rows bucketed by row>>8; requires N <= 131072

    char* p = (char*)d_ws;
    auto alloc = [&](size_t bytes) {
        char* q = p;
        p += (bytes + 255) & ~(size_t)255;
        return q;
    };
    int*   bcnt  = (int*)alloc((size_t)(NBK) * 4);
    int*   bbase = (int*)alloc((size_t)(NBK + 1) * 4);
    int*   bcur  = (int*)alloc((size_t)(NBK) * 4);
    int*   off   = (int*)alloc((size_t)(N + 1) * 4);
    float* dis   = (float*)alloc((size_t)N * 4);
    int*   csr   = (int*)alloc((size_t)E * 4);
    int*   packed = (int*)alloc((size_t)E * 4);
    unsigned short* wp1 = (unsigned short*)alloc(8192 * 2);
    unsigned short* wpx = (unsigned short*)alloc(8192 * 2);
    unsigned short* wp2 = (unsigned short*)alloc(2048 * 2);
    unsigned short* y  = (unsigned short*)alloc((size_t)N * 64 * 2);
    unsigned short* y2 = (unsigned short*)alloc((size_t)N * 64 * 2);
    unsigned short* xb = (unsigned short*)alloc((size_t)N * 64 * 2);
    unsigned short* h  = (unsigned short*)alloc((size_t)N * 64 * 2);
    unsigned short* h2 = (unsigned short*)alloc((size_t)N * 64 * 2);
    (void)ws_size;

    int EB = (E + EPB - 1) / EPB;
    wconv_all<<<72, 256, 0, stream>>>(W1_0, W1_1, Wx_0, Wx_1, W2_0, W2_1,
                                      wp1, wpx, wp2, bcnt, NBK);
    bucket_count<<<EB, 256, 0, stream>>>(row, bcnt, E, NBK);
    bucket_scan<<<1, 256, 0, stream>>>(bcnt, bbase, bcur, off, NBK, N, E);
    bucket_scatter<<<EB, 256, 0, stream>>>(row, col, bcur, packed, E, NBK);
    bucket_build<<<NBK, 256, 0, stream>>>(packed, bbase, x, off, dis, csr, y, xb, N);

    int nb64 = (N + 63) / 64;
    // layer 1: gather from y, dense on [xb | tx] -> h, next-layer y2
    agg_dense<64, true, true><<<nb64, 256, 0, stream>>>(y, xb, csr, off, dis, wp1, b1, h, y2, nullptr, N);
    // layer x: gather from y2, dense on [h | tx] -> h2, next-layer y
    agg_dense<64, true, true><<<nb64, 256, 0, stream>>>(y2, h, csr, off, dis, wpx, bx, h2, y, nullptr, N);
    // layer 2: gather from y, dense on [h2 | tx] -> out (fp32)
    agg_dense<16, false, false><<<nb64, 256, 0, stream>>>(y, h2, csr, off, dis, wp2, b2, nullptr, nullptr, out, N);
}

// Round 17
// 179.486 us; speedup vs baseline: 1.2194x; 1.0372x over previous
//
#include <hip/hip_runtime.h>
#include <hip/hip_bf16.h>

// Two-level counting-sort CSR build:
//   bucket = row >> 8  (256 rows per bucket, NBK = ceil(N/256) <= 512 for N <= 131072)
//   packed edge record = (localrow << 17) | col   (needs N <= 2^17)

#define EPB 4096  // edges per block in bucket count/scatter

typedef __attribute__((ext_vector_type(8))) short bf16x8;
typedef __attribute__((ext_vector_type(4))) float f32x4;

__device__ __forceinline__ float bf2f(unsigned short u) {
    unsigned int x = ((unsigned int)u) << 16;
    return __uint_as_float(x);
}
__device__ __forceinline__ unsigned short f2bf(float f) {
    unsigned int b = __float_as_uint(f);
    unsigned int r = (b + 0x7FFF + ((b >> 16) & 1)) >> 16;  // round-nearest-even
    return (unsigned short)r;
}
__device__ __forceinline__ void acc8(float* a, bf16x8 v) {
#pragma unroll
    for (int i = 0; i < 8; ++i) a[i] += bf2f((unsigned short)(short)v[i]);
}
// masked accumulate: adds exact 0.0f for masked-off lanes (identity)
__device__ __forceinline__ void acc8m(float* a, bf16x8 v, bool m) {
#pragma unroll
    for (int i = 0; i < 8; ++i) a[i] += m ? bf2f((unsigned short)(short)v[i]) : 0.0f;
}
__device__ __forceinline__ void acc4(float* a, ushort4 v) {
    a[0] += bf2f(v.x); a[1] += bf2f(v.y); a[2] += bf2f(v.z); a[3] += bf2f(v.w);
}
__device__ __forceinline__ void acc4m(float* a, ushort4 v, bool m) {
    a[0] += m ? bf2f(v.x) : 0.0f;
    a[1] += m ? bf2f(v.y) : 0.0f;
    a[2] += m ? bf2f(v.z) : 0.0f;
    a[3] += m ? bf2f(v.w) : 0.0f;
}

// ---- one-shot weight convert+pack to MFMA fragment order (+ bcnt zeroing) ----
// K=128 pair: packed idx = ((kt*NT + nt)*4 + g)*128 + m*8 + i
//   <-> source  k = (kt&1)*32 + g*8 + i (from W0 if kt<2 else W1), col = nt*16 + m
template <int NC>
__device__ __forceinline__ void pack_pair(const float* __restrict__ W0,
                                          const float* __restrict__ W1,
                                          unsigned short* __restrict__ out, int idx) {
    constexpr int NT = NC / 16;
    int i = idx & 7;
    int m = (idx >> 3) & 15;
    int g = (idx >> 7) & 3;
    int f = idx >> 9;  // kt*NT + nt
    int nt = f % NT;
    int kt = f / NT;
    const float* W = (kt < 2) ? W0 : W1;
    int k = (kt & 1) * 32 + g * 8 + i;
    out[idx] = f2bf(W[k * NC + nt * 16 + m]);
}
// K=64 single 64x16 weight: idx in [0,1024): kt = idx>>9 (0..1), k = kt*32+g*8+i
__device__ __forceinline__ void pack_single16(const float* __restrict__ W,
                                              unsigned short* __restrict__ out, int idx) {
    int i = idx & 7;
    int m = (idx >> 3) & 15;
    int g = (idx >> 7) & 3;
    int kt = idx >> 9;
    int k = kt * 32 + g * 8 + i;
    out[idx] = f2bf(W[k * 16 + m]);
}

__global__ __launch_bounds__(256) void wconv_all(const float* __restrict__ W1_0,
                                                 const float* __restrict__ W1_1,
                                                 const float* __restrict__ Wx_0,
                                                 const float* __restrict__ Wx_1,
                                                 const float* __restrict__ W2_0,
                                                 const float* __restrict__ W2_1,
                                                 unsigned short* __restrict__ wp1,
                                                 unsigned short* __restrict__ wpx,
                                                 unsigned short* __restrict__ wp2a,
                                                 unsigned short* __restrict__ wp2b,
                                                 int* __restrict__ bcnt, int nbk) {
    int idx = blockIdx.x * 256 + threadIdx.x;
    if (idx < nbk) bcnt[idx] = 0;
    if (idx < 8192) pack_pair<64>(W1_0, W1_1, wp1, idx);
    else if (idx < 16384) pack_pair<64>(Wx_0, Wx_1, wpx, idx - 8192);
    else if (idx < 17408) pack_single16(W2_0, wp2a, idx - 16384);
    else if (idx < 18432) pack_single16(W2_1, wp2b, idx - 17408);
}

// ---- Pass A1: per-bucket edge counts ----
__global__ __launch_bounds__(256) void bucket_count(const int* __restrict__ row,
                                                    int* __restrict__ bcnt,
                                                    int e, int nbk) {
    __shared__ int bh[512];
    int tid = threadIdx.x;
    for (int j = tid; j < nbk; j += 256) bh[j] = 0;
    __syncthreads();
    int base = blockIdx.x * EPB;
#pragma unroll
    for (int k = 0; k < EPB / 256; ++k) {
        int i = base + k * 256 + tid;
        if (i < e) atomicAdd(&bh[row[i] >> 8], 1);
    }
    __syncthreads();
    for (int j = tid; j < nbk; j += 256) {
        int c = bh[j];
        if (c) atomicAdd(&bcnt[j], c);
    }
}

// ---- Pass A2: scan bucket counts (single block) ----
__global__ __launch_bounds__(256) void bucket_scan(const int* __restrict__ bcnt,
                                                   int* __restrict__ bbase,
                                                   int* __restrict__ bcursor,
                                                   int* __restrict__ off,
                                                   int nbk, int n, int e) {
    __shared__ int sa[512], sb[512];
    int tid = threadIdx.x;
    for (int j = tid; j < 512; j += 256) sa[j] = (j < nbk) ? bcnt[j] : 0;
    __syncthreads();
    int* in = sa;
    int* out = sb;
    for (int d = 1; d < 512; d <<= 1) {
        for (int j = tid; j < 512; j += 256)
            out[j] = in[j] + ((j >= d) ? in[j - d] : 0);
        __syncthreads();
        int* t = in; in = out; out = t;
    }
    for (int j = tid; j < nbk; j += 256) {
        int incl = in[j];
        int excl = incl - bcnt[j];
        bbase[j] = excl;
        bcursor[j] = excl;
        if (j == nbk - 1) bbase[nbk] = incl;
    }
    if (tid == 0) off[n] = e;
}

// ---- Pass A3: scatter packed edges into bucket regions ----
__global__ __launch_bounds__(256) void bucket_scatter(const int* __restrict__ row,
                                                      const int* __restrict__ col,
                                                      int* __restrict__ bcursor,
                                                      int* __restrict__ packed,
                                                      int e, int nbk) {
    __shared__ int bh[512];
    __shared__ int bbase[512];
    __shared__ int bcur[512];
    int tid = threadIdx.x;
    for (int j = tid; j < nbk; j += 256) { bh[j] = 0; bcur[j] = 0; }
    __syncthreads();
    int base = blockIdx.x * EPB;
#pragma unroll
    for (int k = 0; k < EPB / 256; ++k) {
        int i = base + k * 256 + tid;
        if (i < e) atomicAdd(&bh[row[i] >> 8], 1);
    }
    __syncthreads();
    for (int j = tid; j < nbk; j += 256) {
        int c = bh[j];
        bbase[j] = c ? atomicAdd(&bcursor[j], c) : 0;
    }
    __syncthreads();
#pragma unroll
    for (int k = 0; k < EPB / 256; ++k) {
        int i = base + k * 256 + tid;
        if (i < e) {
            int r = row[i];
            int b = r >> 8;
            int slot = bbase[b] + atomicAdd(&bcur[b], 1);
            packed[slot] = ((r & 255) << 17) | col[i];
        }
    }
}

// ---- Pass B: per-bucket row histogram + scan -> off/dis/csr; fused y/xb scale ----
__global__ __launch_bounds__(256) void bucket_build(const int* __restrict__ packed,
                                                    const int* __restrict__ bbase,
                                                    const float* __restrict__ x,
                                                    int* __restrict__ off,
                                                    float* __restrict__ dis,
                                                    int* __restrict__ csr,
                                                    unsigned short* __restrict__ y,
                                                    unsigned short* __restrict__ xb,
                                                    int n) {
    __shared__ int rcnt[256];
    __shared__ int sa[256], sb[256];
    __shared__ float disv[256];
    int tid = threadIdx.x;
    int b = blockIdx.x;
    int ebase = bbase[b], eend = bbase[b + 1];
    rcnt[tid] = 0;
    __syncthreads();
    for (int e = ebase + tid; e < eend; e += 256)
        atomicAdd(&rcnt[packed[e] >> 17], 1);
    __syncthreads();
    sa[tid] = rcnt[tid];
    __syncthreads();
    int* in = sa;
    int* out = sb;
    for (int d = 1; d < 256; d <<= 1) {
        out[tid] = in[tid] + ((tid >= d) ? in[tid - d] : 0);
        __syncthreads();
        int* t = in; in = out; out = t;
    }
    // in[tid] = inclusive scan; out is free for reuse as cursor
    int grow = b * 256 + tid;
    int c = rcnt[tid];
    int excl = in[tid] - c;
    float dv = (c > 0) ? rsqrtf((float)c) : 0.0f;
    disv[tid] = dv;
    if (grow < n) {
        off[grow] = ebase + excl;
        dis[grow] = dv;
    }
    out[tid] = excl;
    __syncthreads();
    for (int e = ebase + tid; e < eend; e += 256) {
        int p = packed[e];
        int lr = p >> 17;
        int pos = atomicAdd(&out[lr], 1);
        csr[ebase + pos] = p & 0x1FFFF;
    }
    // fused scale pass: y = bf16(dis*x), xb = bf16(x) for this bucket's 256 rows
    for (int idx = tid; idx < 4096; idx += 256) {
        int rr = idx >> 4, q = idx & 15;
        int R = b * 256 + rr;
        if (R < n) {
            float d = disv[rr];
            float4 v = ((const float4*)x)[(size_t)R * 16 + q];
            ushort4 o = {f2bf(v.x * d), f2bf(v.y * d), f2bf(v.z * d), f2bf(v.w * d)};
            ((ushort4*)y)[(size_t)R * 16 + q] = o;
            ushort4 xo = {f2bf(v.x), f2bf(v.y), f2bf(v.z), f2bf(v.w)};
            ((ushort4*)xb)[(size_t)R * 16 + q] = xo;
        }
    }
}

// ---------------- fused aggregate + dense for 64-col layers (round-13, best measured) ----------------

template <bool RELU>
__global__ __launch_bounds__(256) void agg_dense(const unsigned short* __restrict__ y,
                                                 const unsigned short* __restrict__ A0,
                                                 const int* __restrict__ csr,
                                                 const int* __restrict__ off,
                                                 const float* __restrict__ dis,
                                                 const unsigned short* __restrict__ Wp,
                                                 const float* __restrict__ bias,
                                                 unsigned short* __restrict__ hout,
                                                 unsigned short* __restrict__ yout,
                                                 int n) {
    constexpr int NT = 4;
    __shared__ unsigned short txl[64 * 64];  // 8 KB, [row][col] bf16, swizzled
    int tid = threadIdx.x;

    // ---- phase 1: gather ----
    int row_l = tid >> 2;  // 0..63
    int fq = tid & 3;      // 16-feature quarter
    int r = blockIdx.x * 64 + row_l;
    float acc16[16];
#pragma unroll
    for (int i = 0; i < 16; ++i) acc16[i] = 0.f;
    float d = 0.f;
    if (r < n) {
        int s0 = off[r], e1 = off[r + 1];
        const unsigned short* Yb = y + fq * 16;
        int e1m = e1 - 1;
        for (int t = s0; t < e1; t += 4) {
            int t1 = (t + 1 < e1) ? t + 1 : e1m;
            int t2 = (t + 2 < e1) ? t + 2 : e1m;
            int t3 = (t + 3 < e1) ? t + 3 : e1m;
            int c0 = csr[t], c1 = csr[t1], c2 = csr[t2], c3 = csr[t3];
            const bf16x8* p0 = (const bf16x8*)(Yb + (size_t)c0 * 64);
            const bf16x8* p1 = (const bf16x8*)(Yb + (size_t)c1 * 64);
            const bf16x8* p2 = (const bf16x8*)(Yb + (size_t)c2 * 64);
            const bf16x8* p3 = (const bf16x8*)(Yb + (size_t)c3 * 64);
            bf16x8 v00 = p0[0], v01 = p0[1];
            bf16x8 v10 = p1[0], v11 = p1[1];
            bf16x8 v20 = p2[0], v21 = p2[1];
            bf16x8 v30 = p3[0], v31 = p3[1];
            bool m1 = t + 1 < e1, m2 = t + 2 < e1, m3 = t + 3 < e1;
            acc8(acc16, v00); acc8(acc16 + 8, v01);
            acc8m(acc16, v10, m1); acc8m(acc16 + 8, v11, m1);
            acc8m(acc16, v20, m2); acc8m(acc16 + 8, v21, m2);
            acc8m(acc16, v30, m3); acc8m(acc16 + 8, v31, m3);
        }
        d = -dis[r];
    }
    bf16x8 ov0, ov1;
#pragma unroll
    for (int i = 0; i < 8; ++i) {
        ov0[i] = (short)f2bf(acc16[i] * d);
        ov1[i] = (short)f2bf(acc16[8 + i] * d);
    }
    int swz = (row_l & 7) << 4;
    int cb = fq * 32;
    *(bf16x8*)((char*)txl + row_l * 128 + (cb ^ swz)) = ov0;
    *(bf16x8*)((char*)txl + row_l * 128 + ((cb + 16) ^ swz)) = ov1;
    __syncthreads();

    // ---- phase 2: MFMA ----
    int lane = tid & 63;
    int m = lane & 15;
    int g = lane >> 4;
    int w = tid >> 6;
    const bf16x8* WP = (const bf16x8*)Wp;
    bf16x8 bf[NT][4];
#pragma unroll
    for (int kt = 0; kt < 4; ++kt)
#pragma unroll
        for (int nt = 0; nt < NT; ++nt)
            bf[nt][kt] = WP[((kt * NT + nt) * 4 + g) * 16 + m];
    int r0 = blockIdx.x * 64 + w * 16;
    int ra = r0 + m;
    if (ra > n - 1) ra = n - 1;  // clamped read; write masked below
    const unsigned short* q0 = A0 + (size_t)ra * 64 + g * 8;
    bf16x8 a0 = *(const bf16x8*)q0;
    bf16x8 a1 = *(const bf16x8*)(q0 + 32);
    int rl2 = w * 16 + m;  // rl2 & 7 == m & 7 (w*16 is a multiple of 16)
    int sw2 = (m & 7) << 4;
    bf16x8 a2 = *(bf16x8*)((char*)txl + rl2 * 128 + ((g * 16) ^ sw2));
    bf16x8 a3 = *(bf16x8*)((char*)txl + rl2 * 128 + ((64 + g * 16) ^ sw2));
    f32x4 acc[NT];
#pragma unroll
    for (int nt = 0; nt < NT; ++nt) {
        float b = bias[nt * 16 + m];
        acc[nt][0] = b; acc[nt][1] = b; acc[nt][2] = b; acc[nt][3] = b;
    }
#pragma unroll
    for (int nt = 0; nt < NT; ++nt) {
        acc[nt] = __builtin_amdgcn_mfma_f32_16x16x32_bf16(a0, bf[nt][0], acc[nt], 0, 0, 0);
        acc[nt] = __builtin_amdgcn_mfma_f32_16x16x32_bf16(a1, bf[nt][1], acc[nt], 0, 0, 0);
        acc[nt] = __builtin_amdgcn_mfma_f32_16x16x32_bf16(a2, bf[nt][2], acc[nt], 0, 0, 0);
        acc[nt] = __builtin_amdgcn_mfma_f32_16x16x32_bf16(a3, bf[nt][3], acc[nt], 0, 0, 0);
    }
#pragma unroll
    for (int reg = 0; reg < 4; ++reg) {
        int rr = r0 + 4 * g + reg;
        if (rr >= n) continue;
        float dv = dis[rr];
#pragma unroll
        for (int nt = 0; nt < NT; ++nt) {
            float v = acc[nt][reg];
            if (RELU) v = fmaxf(v, 0.f);
            hout[(size_t)rr * 64 + nt * 16 + m] = f2bf(v);
            yout[(size_t)rr * 64 + nt * 16 + m] = f2bf(v * dv);
        }
    }
}

// ---------------- project16: yp = y @ W2_1 (N x 16, bf16) ----------------
// Aggregation is linear, so layer-2's tx@W2_1 = -dis*sum(yp[col]) — pre-projecting
// shrinks the gather table 12.8 MB -> 3.2 MB (fits one XCD L2) and the per-edge
// payload 128 B -> 32 B. Grid-stride 16-row tiles, verified MFMA mapping.

__global__ __launch_bounds__(256) void project16(const unsigned short* __restrict__ y,
                                                 const unsigned short* __restrict__ Wp,
                                                 unsigned short* __restrict__ yp,
                                                 int n, int nrb) {
    int lane = threadIdx.x & 63;
    int m = lane & 15;
    int g = lane >> 4;
    const bf16x8* WP = (const bf16x8*)Wp;
    bf16x8 b0 = WP[(0 * 4 + g) * 16 + m];
    bf16x8 b1 = WP[(1 * 4 + g) * 16 + m];
    int wrb = blockIdx.x * 4 + (threadIdx.x >> 6);
    int stride = gridDim.x * 4;
    for (int rb = wrb; rb < nrb; rb += stride) {
        int r0 = rb * 16;
        int ra = r0 + m;
        if (ra > n - 1) ra = n - 1;
        const unsigned short* q0 = y + (size_t)ra * 64 + g * 8;
        bf16x8 a0 = *(const bf16x8*)q0;
        bf16x8 a1 = *(const bf16x8*)(q0 + 32);
        f32x4 acc = {0.f, 0.f, 0.f, 0.f};
        acc = __builtin_amdgcn_mfma_f32_16x16x32_bf16(a0, b0, acc, 0, 0, 0);
        acc = __builtin_amdgcn_mfma_f32_16x16x32_bf16(a1, b1, acc, 0, 0, 0);
#pragma unroll
        for (int reg = 0; reg < 4; ++reg) {
            int rr = r0 + 4 * g + reg;
            if (rr < n) yp[(size_t)rr * 16 + m] = f2bf(acc[reg]);
        }
    }
}

// ---------------- layer-2 fused: out = h2 @ W2_0 + (-dis * sum yp[col]) + b ----------------
// Phase 1: 64 rows/block, 4 threads/row x 4 feats (ushort4 8 B loads from yp),
//          masked 8-edge unroll (8 loads in flight). tx16 -> LDS [64][20] bf16.
// Phase 2: 4 waves x 16-row tiles: 2 MFMAs (h2 @ W2_0, K=64) + tx16 + bias, fp32 out.

__global__ __launch_bounds__(256) void agg16(const unsigned short* __restrict__ yp,
                                             const unsigned short* __restrict__ h2,
                                             const int* __restrict__ csr,
                                             const int* __restrict__ off,
                                             const float* __restrict__ dis,
                                             const unsigned short* __restrict__ Wp,
                                             const float* __restrict__ bias,
                                             float* __restrict__ outp,
                                             int n) {
    __shared__ unsigned short t16[64][20];  // 2.5 KB, row stride 40 B (8B-aligned)
    int tid = threadIdx.x;

    // ---- phase 1: gather from yp ----
    int row_l = tid >> 2;  // 0..63
    int fq = tid & 3;      // feature quad (4 bf16 = 8 B)
    int r = blockIdx.x * 64 + row_l;
    float a4[4] = {0.f, 0.f, 0.f, 0.f};
    float d = 0.f;
    if (r < n) {
        int s0 = off[r], e1 = off[r + 1];
        int e1m = e1 - 1;
        const unsigned short* Yq = yp + fq * 4;
        for (int t = s0; t < e1; t += 8) {
            int i1 = (t + 1 < e1) ? t + 1 : e1m;
            int i2 = (t + 2 < e1) ? t + 2 : e1m;
            int i3 = (t + 3 < e1) ? t + 3 : e1m;
            int i4 = (t + 4 < e1) ? t + 4 : e1m;
            int i5 = (t + 5 < e1) ? t + 5 : e1m;
            int i6 = (t + 6 < e1) ? t + 6 : e1m;
            int i7 = (t + 7 < e1) ? t + 7 : e1m;
            int c0 = csr[t],  c1 = csr[i1], c2 = csr[i2], c3 = csr[i3];
            int c4 = csr[i4], c5 = csr[i5], c6 = csr[i6], c7 = csr[i7];
            ushort4 v0 = *(const ushort4*)(Yq + (size_t)c0 * 16);
            ushort4 v1 = *(const ushort4*)(Yq + (size_t)c1 * 16);
            ushort4 v2 = *(const ushort4*)(Yq + (size_t)c2 * 16);
            ushort4 v3 = *(const ushort4*)(Yq + (size_t)c3 * 16);
            ushort4 v4 = *(const ushort4*)(Yq + (size_t)c4 * 16);
            ushort4 v5 = *(const ushort4*)(Yq + (size_t)c5 * 16);
            ushort4 v6 = *(const ushort4*)(Yq + (size_t)c6 * 16);
            ushort4 v7 = *(const ushort4*)(Yq + (size_t)c7 * 16);
            bool m1 = t + 1 < e1, m2 = t + 2 < e1, m3 = t + 3 < e1;
            bool m4 = t + 4 < e1, m5 = t + 5 < e1, m6 = t + 6 < e1, m7 = t + 7 < e1;
            acc4(a4, v0);
            acc4m(a4, v1, m1); acc4m(a4, v2, m2); acc4m(a4, v3, m3);
            acc4m(a4, v4, m4); acc4m(a4, v5, m5); acc4m(a4, v6, m6); acc4m(a4, v7, m7);
        }
        d = -dis[r];
    }
    ushort4 ov = {f2bf(a4[0] * d), f2bf(a4[1] * d), f2bf(a4[2] * d), f2bf(a4[3] * d)};
    *(ushort4*)&t16[row_l][fq * 4] = ov;
    __syncthreads();

    // ---- phase 2: MFMA h2 @ W2_0 + tx16 + bias ----
    int lane = tid & 63;
    int m = lane & 15;
    int g = lane >> 4;
    int w = tid >> 6;
    const bf16x8* WP = (const bf16x8*)Wp;
    bf16x8 b0 = WP[(0 * 4 + g) * 16 + m];
    bf16x8 b1 = WP[(1 * 4 + g) * 16 + m];
    int r0 = blockIdx.x * 64 + w * 16;
    int ra = r0 + m;
    if (ra > n - 1) ra = n - 1;  // clamped read; write masked below
    const unsigned short* q0 = h2 + (size_t)ra * 64 + g * 8;
    bf16x8 a0 = *(const bf16x8*)q0;
    bf16x8 a1 = *(const bf16x8*)(q0 + 32);
    f32x4 acc;
    {
        float b = bias[m];
        acc[0] = b; acc[1] = b; acc[2] = b; acc[3] = b;
    }
    acc = __builtin_amdgcn_mfma_f32_16x16x32_bf16(a0, b0, acc, 0, 0, 0);
    acc = __builtin_amdgcn_mfma_f32_16x16x32_bf16(a1, b1, acc, 0, 0, 0);
#pragma unroll
    for (int reg = 0; reg < 4; ++reg) {
        int rr = r0 + 4 * g + reg;
        if (rr >= n) continue;
        int lrow = w * 16 + 4 * g + reg;
        outp[(size_t)rr * 16 + m] = acc[reg] + bf2f(t16[lrow][m]);
    }
}

// ---------------- launch ----------------

extern "C" void kernel_launch(void* const* d_in, const int* in_sizes, int n_in,
                              void* d_out, int out_size, void* d_ws, size_t ws_size,
                              hipStream_t stream) {
    const float* x    = (const float*)d_in[0];
    const int*   adj  = (const int*)d_in[1];
    const float* W1_0 = (const float*)d_in[2];
    const float* W1_1 = (const float*)d_in[3];
    const float* b1   = (const float*)d_in[4];
    const float* Wx_0 = (const float*)d_in[5];
    const float* Wx_1 = (const float*)d_in[6];
    const float* bx   = (const float*)d_in[7];
    const float* W2_0 = (const float*)d_in[8];
    const float* W2_1 = (const float*)d_in[9];
    const float* b2   = (const float*)d_in[10];
    float* out = (float*)d_out;

    int N = in_sizes[0] / 64;
    int E = in_sizes[1] / 2;
    const int* row = adj;
    const int* col = adj + E;
    int NBK = (N + 255) / 256;  // rows bucketed by row>>8; requires N <= 131072
    int nRB = (N + 15) / 16;

    char* p = (char*)d_ws;
    auto alloc = [&](size_t bytes) {
        char* q = p;
        p += (bytes + 255) & ~(size_t)255;
        return q;
    };
    int*   bcnt  = (int*)alloc((size_t)(NBK) * 4);
    int*   bbase = (int*)alloc((size_t)(NBK + 1) * 4);
    int*   bcur  = (int*)alloc((size_t)(NBK) * 4);
    int*   off   = (int*)alloc((size_t)(N + 1) * 4);
    float* dis   = (float*)alloc((size_t)N * 4);
    int*   csr   = (int*)alloc((size_t)E * 4);
    int*   packed = (int*)alloc((size_t)E * 4);
    unsigned short* wp1  = (unsigned short*)alloc(8192 * 2);
    unsigned short* wpx  = (unsigned short*)alloc(8192 * 2);
    unsigned short* wp2a = (unsigned short*)alloc(1024 * 2);
    unsigned short* wp2b = (unsigned short*)alloc(1024 * 2);
    unsigned short* y  = (unsigned short*)alloc((size_t)N * 64 * 2);
    unsigned short* y2 = (unsigned short*)alloc((size_t)N * 64 * 2);
    unsigned short* xb = (unsigned short*)alloc((size_t)N * 64 * 2);
    unsigned short* h  = (unsigned short*)alloc((size_t)N * 64 * 2);
    unsigned short* h2 = (unsigned short*)alloc((size_t)N * 64 * 2);
    unsigned short* yp = (unsigned short*)alloc((size_t)N * 16 * 2);
    (void)ws_size;

    int EB = (E + EPB - 1) / EPB;
    wconv_all<<<72, 256, 0, stream>>>(W1_0, W1_1, Wx_0, Wx_1, W2_0, W2_1,
                                      wp1, wpx, wp2a, wp2b, bcnt, NBK);
    bucket_count<<<EB, 256, 0, stream>>>(row, bcnt, E, NBK);
    bucket_scan<<<1, 256, 0, stream>>>(bcnt, bbase, bcur, off, NBK, N, E);
    bucket_scatter<<<EB, 256, 0, stream>>>(row, col, bcur, packed, E, NBK);
    bucket_build<<<NBK, 256, 0, stream>>>(packed, bbase, x, off, dis, csr, y, xb, N);

    int nb64 = (N + 63) / 64;
    // layer 1: gather from y, dense on [xb | tx] -> h, next-layer y2
    agg_dense<true><<<nb64, 256, 0, stream>>>(y, xb, csr, off, dis, wp1, b1, h, y2, N);
    // layer x: gather from y2, dense on [h | tx] -> h2, next-layer y (= dis*h2)
    agg_dense<true><<<nb64, 256, 0, stream>>>(y2, h, csr, off, dis, wpx, bx, h2, y, N);
    // layer 2: pre-project y -> yp (N x 16), gather from yp, dense h2@W2_0 + tx16
    project16<<<512, 256, 0, stream>>>(y, wp2b, yp, N, nRB);
    agg16<<<nb64, 256, 0, stream>>>(yp, h2, csr, off, dis, wp2a, b2, out, N);
}

// Round 18
// 172.310 us; speedup vs baseline: 1.2702x; 1.0416x over previous
//
#include <hip/hip_runtime.h>
#include <hip/hip_bf16.h>

// Two-level counting-sort CSR build:
//   bucket = row >> 8  (256 rows per bucket, NBK = ceil(N/256) <= 512 for N <= 131072)
//   packed edge record = (localrow << 17) | col   (needs N <= 2^17)

#define EPB 4096  // edges per block in bucket count/scatter

typedef __attribute__((ext_vector_type(8))) short bf16x8;
typedef __attribute__((ext_vector_type(4))) float f32x4;

__device__ __forceinline__ float bf2f(unsigned short u) {
    unsigned int x = ((unsigned int)u) << 16;
    return __uint_as_float(x);
}
__device__ __forceinline__ unsigned short f2bf(float f) {
    unsigned int b = __float_as_uint(f);
    unsigned int r = (b + 0x7FFF + ((b >> 16) & 1)) >> 16;  // round-nearest-even
    return (unsigned short)r;
}
__device__ __forceinline__ void acc8(float* a, bf16x8 v) {
#pragma unroll
    for (int i = 0; i < 8; ++i) a[i] += bf2f((unsigned short)(short)v[i]);
}
// masked accumulate: adds exact 0.0f for masked-off lanes (identity)
__device__ __forceinline__ void acc8m(float* a, bf16x8 v, bool m) {
#pragma unroll
    for (int i = 0; i < 8; ++i) a[i] += m ? bf2f((unsigned short)(short)v[i]) : 0.0f;
}
__device__ __forceinline__ void acc4(float* a, ushort4 v) {
    a[0] += bf2f(v.x); a[1] += bf2f(v.y); a[2] += bf2f(v.z); a[3] += bf2f(v.w);
}
__device__ __forceinline__ void acc4m(float* a, ushort4 v, bool m) {
    a[0] += m ? bf2f(v.x) : 0.0f;
    a[1] += m ? bf2f(v.y) : 0.0f;
    a[2] += m ? bf2f(v.z) : 0.0f;
    a[3] += m ? bf2f(v.w) : 0.0f;
}

// ---- one-shot weight convert+pack to MFMA fragment order (+ bcnt zeroing) ----
// K=128 pair: packed idx = ((kt*NT + nt)*4 + g)*128 + m*8 + i
//   <-> source  k = (kt&1)*32 + g*8 + i (from W0 if kt<2 else W1), col = nt*16 + m
template <int NC>
__device__ __forceinline__ void pack_pair(const float* __restrict__ W0,
                                          const float* __restrict__ W1,
                                          unsigned short* __restrict__ out, int idx) {
    constexpr int NT = NC / 16;
    int i = idx & 7;
    int m = (idx >> 3) & 15;
    int g = (idx >> 7) & 3;
    int f = idx >> 9;  // kt*NT + nt
    int nt = f % NT;
    int kt = f / NT;
    const float* W = (kt < 2) ? W0 : W1;
    int k = (kt & 1) * 32 + g * 8 + i;
    out[idx] = f2bf(W[k * NC + nt * 16 + m]);
}
// K=64 single 64x16 weight: idx in [0,1024): kt = idx>>9 (0..1), k = kt*32+g*8+i
__device__ __forceinline__ void pack_single16(const float* __restrict__ W,
                                              unsigned short* __restrict__ out, int idx) {
    int i = idx & 7;
    int m = (idx >> 3) & 15;
    int g = (idx >> 7) & 3;
    int kt = idx >> 9;
    int k = kt * 32 + g * 8 + i;
    out[idx] = f2bf(W[k * 16 + m]);
}

__global__ __launch_bounds__(256) void wconv_all(const float* __restrict__ W1_0,
                                                 const float* __restrict__ W1_1,
                                                 const float* __restrict__ Wx_0,
                                                 const float* __restrict__ Wx_1,
                                                 const float* __restrict__ W2_0,
                                                 const float* __restrict__ W2_1,
                                                 unsigned short* __restrict__ wp1,
                                                 unsigned short* __restrict__ wpx,
                                                 unsigned short* __restrict__ wp2a,
                                                 unsigned short* __restrict__ wp2b,
                                                 int* __restrict__ bcnt, int nbk) {
    int idx = blockIdx.x * 256 + threadIdx.x;
    if (idx < nbk) bcnt[idx] = 0;
    if (idx < 8192) pack_pair<64>(W1_0, W1_1, wp1, idx);
    else if (idx < 16384) pack_pair<64>(Wx_0, Wx_1, wpx, idx - 8192);
    else if (idx < 17408) pack_single16(W2_0, wp2a, idx - 16384);
    else if (idx < 18432) pack_single16(W2_1, wp2b, idx - 17408);
}

// ---- Pass A1: per-bucket edge counts ----
__global__ __launch_bounds__(256) void bucket_count(const int* __restrict__ row,
                                                    int* __restrict__ bcnt,
                                                    int e, int nbk) {
    __shared__ int bh[512];
    int tid = threadIdx.x;
    for (int j = tid; j < nbk; j += 256) bh[j] = 0;
    __syncthreads();
    int base = blockIdx.x * EPB;
#pragma unroll
    for (int k = 0; k < EPB / 256; ++k) {
        int i = base + k * 256 + tid;
        if (i < e) atomicAdd(&bh[row[i] >> 8], 1);
    }
    __syncthreads();
    for (int j = tid; j < nbk; j += 256) {
        int c = bh[j];
        if (c) atomicAdd(&bcnt[j], c);
    }
}

// ---- Pass A2: scan bucket counts (single block) ----
__global__ __launch_bounds__(256) void bucket_scan(const int* __restrict__ bcnt,
                                                   int* __restrict__ bbase,
                                                   int* __restrict__ bcursor,
                                                   int* __restrict__ off,
                                                   int nbk, int n, int e) {
    __shared__ int sa[512], sb[512];
    int tid = threadIdx.x;
    for (int j = tid; j < 512; j += 256) sa[j] = (j < nbk) ? bcnt[j] : 0;
    __syncthreads();
    int* in = sa;
    int* out = sb;
    for (int d = 1; d < 512; d <<= 1) {
        for (int j = tid; j < 512; j += 256)
            out[j] = in[j] + ((j >= d) ? in[j - d] : 0);
        __syncthreads();
        int* t = in; in = out; out = t;
    }
    for (int j = tid; j < nbk; j += 256) {
        int incl = in[j];
        int excl = incl - bcnt[j];
        bbase[j] = excl;
        bcursor[j] = excl;
        if (j == nbk - 1) bbase[nbk] = incl;
    }
    if (tid == 0) off[n] = e;
}

// ---- Pass A3: scatter packed edges into bucket regions ----
__global__ __launch_bounds__(256) void bucket_scatter(const int* __restrict__ row,
                                                      const int* __restrict__ col,
                                                      int* __restrict__ bcursor,
                                                      int* __restrict__ packed,
                                                      int e, int nbk) {
    __shared__ int bh[512];
    __shared__ int bbase[512];
    __shared__ int bcur[512];
    int tid = threadIdx.x;
    for (int j = tid; j < nbk; j += 256) { bh[j] = 0; bcur[j] = 0; }
    __syncthreads();
    int base = blockIdx.x * EPB;
#pragma unroll
    for (int k = 0; k < EPB / 256; ++k) {
        int i = base + k * 256 + tid;
        if (i < e) atomicAdd(&bh[row[i] >> 8], 1);
    }
    __syncthreads();
    for (int j = tid; j < nbk; j += 256) {
        int c = bh[j];
        bbase[j] = c ? atomicAdd(&bcursor[j], c) : 0;
    }
    __syncthreads();
#pragma unroll
    for (int k = 0; k < EPB / 256; ++k) {
        int i = base + k * 256 + tid;
        if (i < e) {
            int r = row[i];
            int b = r >> 8;
            int slot = bbase[b] + atomicAdd(&bcur[b], 1);
            packed[slot] = ((r & 255) << 17) | col[i];
        }
    }
}

// ---- Pass B: per-bucket row histogram + scan -> off/dis/csr; fused y/xb scale ----
__global__ __launch_bounds__(256) void bucket_build(const int* __restrict__ packed,
                                                    const int* __restrict__ bbase,
                                                    const float* __restrict__ x,
                                                    int* __restrict__ off,
                                                    float* __restrict__ dis,
                                                    int* __restrict__ csr,
                                                    unsigned short* __restrict__ y,
                                                    unsigned short* __restrict__ xb,
                                                    int n) {
    __shared__ int rcnt[256];
    __shared__ int sa[256], sb[256];
    __shared__ float disv[256];
    int tid = threadIdx.x;
    int b = blockIdx.x;
    int ebase = bbase[b], eend = bbase[b + 1];
    rcnt[tid] = 0;
    __syncthreads();
    for (int e = ebase + tid; e < eend; e += 256)
        atomicAdd(&rcnt[packed[e] >> 17], 1);
    __syncthreads();
    sa[tid] = rcnt[tid];
    __syncthreads();
    int* in = sa;
    int* out = sb;
    for (int d = 1; d < 256; d <<= 1) {
        out[tid] = in[tid] + ((tid >= d) ? in[tid - d] : 0);
        __syncthreads();
        int* t = in; in = out; out = t;
    }
    // in[tid] = inclusive scan; out is free for reuse as cursor
    int grow = b * 256 + tid;
    int c = rcnt[tid];
    int excl = in[tid] - c;
    float dv = (c > 0) ? rsqrtf((float)c) : 0.0f;
    disv[tid] = dv;
    if (grow < n) {
        off[grow] = ebase + excl;
        dis[grow] = dv;
    }
    out[tid] = excl;
    __syncthreads();
    for (int e = ebase + tid; e < eend; e += 256) {
        int p = packed[e];
        int lr = p >> 17;
        int pos = atomicAdd(&out[lr], 1);
        csr[ebase + pos] = p & 0x1FFFF;
    }
    // fused scale pass: y = bf16(dis*x), xb = bf16(x) for this bucket's 256 rows
    for (int idx = tid; idx < 4096; idx += 256) {
        int rr = idx >> 4, q = idx & 15;
        int R = b * 256 + rr;
        if (R < n) {
            float d = disv[rr];
            float4 v = ((const float4*)x)[(size_t)R * 16 + q];
            ushort4 o = {f2bf(v.x * d), f2bf(v.y * d), f2bf(v.z * d), f2bf(v.w * d)};
            ((ushort4*)y)[(size_t)R * 16 + q] = o;
            ushort4 xo = {f2bf(v.x), f2bf(v.y), f2bf(v.z), f2bf(v.w)};
            ((ushort4*)xb)[(size_t)R * 16 + q] = xo;
        }
    }
}

// ---------------- fused aggregate + dense for 64-col layers (round-13 geometry) ----------------
// PROJ variant (layer x): instead of writing the full-width y table (only needed
// to later compute yp = y @ W2_1), fold the projection in: stash the bf16 y-tile
// into the (free, wave-local) txl LDS with the standard 16B-unit XOR swizzle,
// read back as MFMA A-fragments (same k-labeling as the old project16), and emit
// yp (N x 16) directly. Bit-identical to project16's output; saves one dispatch
// + 12.8 MB y write + 12.8 MB y re-read.

template <bool RELU, bool PROJ>
__global__ __launch_bounds__(256) void agg_dense(const unsigned short* __restrict__ y,
                                                 const unsigned short* __restrict__ A0,
                                                 const int* __restrict__ csr,
                                                 const int* __restrict__ off,
                                                 const float* __restrict__ dis,
                                                 const unsigned short* __restrict__ Wp,
                                                 const float* __restrict__ bias,
                                                 unsigned short* __restrict__ hout,
                                                 unsigned short* __restrict__ yout,
                                                 const unsigned short* __restrict__ Wp2b,
                                                 unsigned short* __restrict__ yp,
                                                 int n) {
    constexpr int NT = 4;
    __shared__ unsigned short txl[64 * 64];  // 8 KB, [row][col] bf16, swizzled
    int tid = threadIdx.x;

    // ---- phase 1: gather ----
    int row_l = tid >> 2;  // 0..63
    int fq = tid & 3;      // 16-feature quarter
    int r = blockIdx.x * 64 + row_l;
    float acc16[16];
#pragma unroll
    for (int i = 0; i < 16; ++i) acc16[i] = 0.f;
    float d = 0.f;
    if (r < n) {
        int s0 = off[r], e1 = off[r + 1];
        const unsigned short* Yb = y + fq * 16;
        int e1m = e1 - 1;
        for (int t = s0; t < e1; t += 4) {
            int t1 = (t + 1 < e1) ? t + 1 : e1m;
            int t2 = (t + 2 < e1) ? t + 2 : e1m;
            int t3 = (t + 3 < e1) ? t + 3 : e1m;
            int c0 = csr[t], c1 = csr[t1], c2 = csr[t2], c3 = csr[t3];
            const bf16x8* p0 = (const bf16x8*)(Yb + (size_t)c0 * 64);
            const bf16x8* p1 = (const bf16x8*)(Yb + (size_t)c1 * 64);
            const bf16x8* p2 = (const bf16x8*)(Yb + (size_t)c2 * 64);
            const bf16x8* p3 = (const bf16x8*)(Yb + (size_t)c3 * 64);
            bf16x8 v00 = p0[0], v01 = p0[1];
            bf16x8 v10 = p1[0], v11 = p1[1];
            bf16x8 v20 = p2[0], v21 = p2[1];
            bf16x8 v30 = p3[0], v31 = p3[1];
            bool m1 = t + 1 < e1, m2 = t + 2 < e1, m3 = t + 3 < e1;
            acc8(acc16, v00); acc8(acc16 + 8, v01);
            acc8m(acc16, v10, m1); acc8m(acc16 + 8, v11, m1);
            acc8m(acc16, v20, m2); acc8m(acc16 + 8, v21, m2);
            acc8m(acc16, v30, m3); acc8m(acc16 + 8, v31, m3);
        }
        d = -dis[r];
    }
    bf16x8 ov0, ov1;
#pragma unroll
    for (int i = 0; i < 8; ++i) {
        ov0[i] = (short)f2bf(acc16[i] * d);
        ov1[i] = (short)f2bf(acc16[8 + i] * d);
    }
    int swz = (row_l & 7) << 4;
    int cb = fq * 32;
    *(bf16x8*)((char*)txl + row_l * 128 + (cb ^ swz)) = ov0;
    *(bf16x8*)((char*)txl + row_l * 128 + ((cb + 16) ^ swz)) = ov1;
    __syncthreads();

    // ---- phase 2: MFMA ----
    int lane = tid & 63;
    int m = lane & 15;
    int g = lane >> 4;
    int w = tid >> 6;
    const bf16x8* WP = (const bf16x8*)Wp;
    bf16x8 bf[NT][4];
#pragma unroll
    for (int kt = 0; kt < 4; ++kt)
#pragma unroll
        for (int nt = 0; nt < NT; ++nt)
            bf[nt][kt] = WP[((kt * NT + nt) * 4 + g) * 16 + m];
    int r0 = blockIdx.x * 64 + w * 16;
    int ra = r0 + m;
    if (ra > n - 1) ra = n - 1;  // clamped read; write masked below
    const unsigned short* q0 = A0 + (size_t)ra * 64 + g * 8;
    bf16x8 a0 = *(const bf16x8*)q0;
    bf16x8 a1 = *(const bf16x8*)(q0 + 32);
    int rl2 = w * 16 + m;  // rl2 & 7 == m & 7 (w*16 is a multiple of 16)
    int sw2 = (m & 7) << 4;
    bf16x8 a2 = *(bf16x8*)((char*)txl + rl2 * 128 + ((g * 16) ^ sw2));
    bf16x8 a3 = *(bf16x8*)((char*)txl + rl2 * 128 + ((64 + g * 16) ^ sw2));
    f32x4 acc[NT];
#pragma unroll
    for (int nt = 0; nt < NT; ++nt) {
        float b = bias[nt * 16 + m];
        acc[nt][0] = b; acc[nt][1] = b; acc[nt][2] = b; acc[nt][3] = b;
    }
#pragma unroll
    for (int nt = 0; nt < NT; ++nt) {
        acc[nt] = __builtin_amdgcn_mfma_f32_16x16x32_bf16(a0, bf[nt][0], acc[nt], 0, 0, 0);
        acc[nt] = __builtin_amdgcn_mfma_f32_16x16x32_bf16(a1, bf[nt][1], acc[nt], 0, 0, 0);
        acc[nt] = __builtin_amdgcn_mfma_f32_16x16x32_bf16(a2, bf[nt][2], acc[nt], 0, 0, 0);
        acc[nt] = __builtin_amdgcn_mfma_f32_16x16x32_bf16(a3, bf[nt][3], acc[nt], 0, 0, 0);
    }
#pragma unroll
    for (int reg = 0; reg < 4; ++reg) {
        int rr = r0 + 4 * g + reg;
        if (rr >= n) continue;
        float dv = dis[rr];
        int row_loc = w * 16 + 4 * g + reg;
#pragma unroll
        for (int nt = 0; nt < NT; ++nt) {
            float v = acc[nt][reg];
            if (RELU) v = fmaxf(v, 0.f);
            hout[(size_t)rr * 64 + nt * 16 + m] = f2bf(v);
            unsigned short yv = f2bf(v * dv);
            if (!PROJ) {
                yout[(size_t)rr * 64 + nt * 16 + m] = yv;
            } else {
                // stash y-tile into txl (wave-local rows), 16B-unit XOR swizzle
                int u = nt * 2 + (m >> 3);
                int byte = row_loc * 128 + ((u ^ (row_loc & 7)) << 4) + (m & 7) * 2;
                *(unsigned short*)((char*)txl + byte) = yv;
            }
        }
    }
    if (PROJ) {
        // yp = y_tile @ W2_1 (identical k-labeling and rounding as old project16)
        const bf16x8* WP2 = (const bf16x8*)Wp2b;
        bf16x8 bp0 = WP2[(0 * 4 + g) * 16 + m];
        bf16x8 bp1 = WP2[(1 * 4 + g) * 16 + m];
        int rla = w * 16 + m;
        int swa = (m & 7) << 4;
        bf16x8 ya0 = *(bf16x8*)((char*)txl + rla * 128 + ((g * 16) ^ swa));
        bf16x8 ya1 = *(bf16x8*)((char*)txl + rla * 128 + ((64 + g * 16) ^ swa));
        f32x4 ap = {0.f, 0.f, 0.f, 0.f};
        ap = __builtin_amdgcn_mfma_f32_16x16x32_bf16(ya0, bp0, ap, 0, 0, 0);
        ap = __builtin_amdgcn_mfma_f32_16x16x32_bf16(ya1, bp1, ap, 0, 0, 0);
#pragma unroll
        for (int reg = 0; reg < 4; ++reg) {
            int rr = r0 + 4 * g + reg;
            if (rr < n) yp[(size_t)rr * 16 + m] = f2bf(ap[reg]);
        }
    }
}

// ---------------- layer-2 fused: out = h2 @ W2_0 + (-dis * sum yp[col]) + b ----------------
// Phase 1: 64 rows/block, 4 threads/row x 4 feats (ushort4 8 B loads from yp),
//          masked 8-edge unroll (8 loads in flight). tx16 -> LDS [64][20] bf16.
// Phase 2: 4 waves x 16-row tiles: 2 MFMAs (h2 @ W2_0, K=64) + tx16 + bias, fp32 out.

__global__ __launch_bounds__(256) void agg16(const unsigned short* __restrict__ yp,
                                             const unsigned short* __restrict__ h2,
                                             const int* __restrict__ csr,
                                             const int* __restrict__ off,
                                             const float* __restrict__ dis,
                                             const unsigned short* __restrict__ Wp,
                                             const float* __restrict__ bias,
                                             float* __restrict__ outp,
                                             int n) {
    __shared__ unsigned short t16[64][20];  // 2.5 KB, row stride 40 B (8B-aligned)
    int tid = threadIdx.x;

    // ---- phase 1: gather from yp ----
    int row_l = tid >> 2;  // 0..63
    int fq = tid & 3;      // feature quad (4 bf16 = 8 B)
    int r = blockIdx.x * 64 + row_l;
    float a4[4] = {0.f, 0.f, 0.f, 0.f};
    float d = 0.f;
    if (r < n) {
        int s0 = off[r], e1 = off[r + 1];
        int e1m = e1 - 1;
        const unsigned short* Yq = yp + fq * 4;
        for (int t = s0; t < e1; t += 8) {
            int i1 = (t + 1 < e1) ? t + 1 : e1m;
            int i2 = (t + 2 < e1) ? t + 2 : e1m;
            int i3 = (t + 3 < e1) ? t + 3 : e1m;
            int i4 = (t + 4 < e1) ? t + 4 : e1m;
            int i5 = (t + 5 < e1) ? t + 5 : e1m;
            int i6 = (t + 6 < e1) ? t + 6 : e1m;
            int i7 = (t + 7 < e1) ? t + 7 : e1m;
            int c0 = csr[t],  c1 = csr[i1], c2 = csr[i2], c3 = csr[i3];
            int c4 = csr[i4], c5 = csr[i5], c6 = csr[i6], c7 = csr[i7];
            ushort4 v0 = *(const ushort4*)(Yq + (size_t)c0 * 16);
            ushort4 v1 = *(const ushort4*)(Yq + (size_t)c1 * 16);
            ushort4 v2 = *(const ushort4*)(Yq + (size_t)c2 * 16);
            ushort4 v3 = *(const ushort4*)(Yq + (size_t)c3 * 16);
            ushort4 v4 = *(const ushort4*)(Yq + (size_t)c4 * 16);
            ushort4 v5 = *(const ushort4*)(Yq + (size_t)c5 * 16);
            ushort4 v6 = *(const ushort4*)(Yq + (size_t)c6 * 16);
            ushort4 v7 = *(const ushort4*)(Yq + (size_t)c7 * 16);
            bool m1 = t + 1 < e1, m2 = t + 2 < e1, m3 = t + 3 < e1;
            bool m4 = t + 4 < e1, m5 = t + 5 < e1, m6 = t + 6 < e1, m7 = t + 7 < e1;
            acc4(a4, v0);
            acc4m(a4, v1, m1); acc4m(a4, v2, m2); acc4m(a4, v3, m3);
            acc4m(a4, v4, m4); acc4m(a4, v5, m5); acc4m(a4, v6, m6); acc4m(a4, v7, m7);
        }
        d = -dis[r];
    }
    ushort4 ov = {f2bf(a4[0] * d), f2bf(a4[1] * d), f2bf(a4[2] * d), f2bf(a4[3] * d)};
    *(ushort4*)&t16[row_l][fq * 4] = ov;
    __syncthreads();

    // ---- phase 2: MFMA h2 @ W2_0 + tx16 + bias ----
    int lane = tid & 63;
    int m = lane & 15;
    int g = lane >> 4;
    int w = tid >> 6;
    const bf16x8* WP = (const bf16x8*)Wp;
    bf16x8 b0 = WP[(0 * 4 + g) * 16 + m];
    bf16x8 b1 = WP[(1 * 4 + g) * 16 + m];
    int r0 = blockIdx.x * 64 + w * 16;
    int ra = r0 + m;
    if (ra > n - 1) ra = n - 1;  // clamped read; write masked below
    const unsigned short* q0 = h2 + (size_t)ra * 64 + g * 8;
    bf16x8 a0 = *(const bf16x8*)q0;
    bf16x8 a1 = *(const bf16x8*)(q0 + 32);
    f32x4 acc;
    {
        float b = bias[m];
        acc[0] = b; acc[1] = b; acc[2] = b; acc[3] = b;
    }
    acc = __builtin_amdgcn_mfma_f32_16x16x32_bf16(a0, b0, acc, 0, 0, 0);
    acc = __builtin_amdgcn_mfma_f32_16x16x32_bf16(a1, b1, acc, 0, 0, 0);
#pragma unroll
    for (int reg = 0; reg < 4; ++reg) {
        int rr = r0 + 4 * g + reg;
        if (rr >= n) continue;
        int lrow = w * 16 + 4 * g + reg;
        outp[(size_t)rr * 16 + m] = acc[reg] + bf2f(t16[lrow][m]);
    }
}

// ---------------- launch ----------------

extern "C" void kernel_launch(void* const* d_in, const int* in_sizes, int n_in,
                              void* d_out, int out_size, void* d_ws, size_t ws_size,
                              hipStream_t stream) {
    const float* x    = (const float*)d_in[0];
    const int*   adj  = (const int*)d_in[1];
    const float* W1_0 = (const float*)d_in[2];
    const float* W1_1 = (const float*)d_in[3];
    const float* b1   = (const float*)d_in[4];
    const float* Wx_0 = (const float*)d_in[5];
    const float* Wx_1 = (const float*)d_in[6];
    const float* bx   = (const float*)d_in[7];
    const float* W2_0 = (const float*)d_in[8];
    const float* W2_1 = (const float*)d_in[9];
    const float* b2   = (const float*)d_in[10];
    float* out = (float*)d_out;

    int N = in_sizes[0] / 64;
    int E = in_sizes[1] / 2;
    const int* row = adj;
    const int* col = adj + E;
    int NBK = (N + 255) / 256;  // rows bucketed by row>>8; requires N <= 131072

    char* p = (char*)d_ws;
    auto alloc = [&](size_t bytes) {
        char* q = p;
        p += (bytes + 255) & ~(size_t)255;
        return q;
    };
    int*   bcnt  = (int*)alloc((size_t)(NBK) * 4);
    int*   bbase = (int*)alloc((size_t)(NBK + 1) * 4);
    int*   bcur  = (int*)alloc((size_t)(NBK) * 4);
    int*   off   = (int*)alloc((size_t)(N + 1) * 4);
    float* dis   = (float*)alloc((size_t)N * 4);
    int*   csr   = (int*)alloc((size_t)E * 4);
    int*   packed = (int*)alloc((size_t)E * 4);
    unsigned short* wp1  = (unsigned short*)alloc(8192 * 2);
    unsigned short* wpx  = (unsigned short*)alloc(8192 * 2);
    unsigned short* wp2a = (unsigned short*)alloc(1024 * 2);
    unsigned short* wp2b = (unsigned short*)alloc(1024 * 2);
    unsigned short* y  = (unsigned short*)alloc((size_t)N * 64 * 2);
    unsigned short* y2 = (unsigned short*)alloc((size_t)N * 64 * 2);
    unsigned short* xb = (unsigned short*)alloc((size_t)N * 64 * 2);
    unsigned short* h  = (unsigned short*)alloc((size_t)N * 64 * 2);
    unsigned short* h2 = (unsigned short*)alloc((size_t)N * 64 * 2);
    unsigned short* yp = (unsigned short*)alloc((size_t)N * 16 * 2);
    (void)ws_size;

    int EB = (E + EPB - 1) / EPB;
    wconv_all<<<72, 256, 0, stream>>>(W1_0, W1_1, Wx_0, Wx_1, W2_0, W2_1,
                                      wp1, wpx, wp2a, wp2b, bcnt, NBK);
    bucket_count<<<EB, 256, 0, stream>>>(row, bcnt, E, NBK);
    bucket_scan<<<1, 256, 0, stream>>>(bcnt, bbase, bcur, off, NBK, N, E);
    bucket_scatter<<<EB, 256, 0, stream>>>(row, col, bcur, packed, E, NBK);
    bucket_build<<<NBK, 256, 0, stream>>>(packed, bbase, x, off, dis, csr, y, xb, N);

    int nb64 = (N + 63) / 64;
    // layer 1: gather from y, dense on [xb | tx] -> h, next-layer y2
    agg_dense<true, false><<<nb64, 256, 0, stream>>>(y, xb, csr, off, dis, wp1, b1, h, y2, nullptr, nullptr, N);
    // layer x: gather from y2, dense on [h | tx] -> h2; fused yp = (dis*h2) @ W2_1
    agg_dense<true, true><<<nb64, 256, 0, stream>>>(y2, h, csr, off, dis, wpx, bx, h2, nullptr, wp2b, yp, N);
    // layer 2: gather from yp (L2-resident 3.2 MB), dense h2@W2_0 + tx16 -> out
    agg16<<<nb64, 256, 0, stream>>>(yp, h2, csr, off, dis, wp2a, b2, out, N);
}